// Round 1
// baseline (252.686 us; speedup 1.0000x reference)
//
#include <hip/hip_runtime.h>
#include <stdint.h>

// ---------------------------------------------------------------------------
// MLP_42872363549033: ViT-B quantized MLP
//   h   = gelu( quant(x,ka1) @ quant(W1,kw1)^T + b1 )
//   out = quant(h,ka2) @ quant(W2,kw2)^T + b2
// quant(x,K) = round(clip(x/K,-1,1)*127)/127 * K  -> exact int8 * (K/127)
// => both GEMMs done exactly in i8 MFMA with i32 accumulation.
// ---------------------------------------------------------------------------

typedef __attribute__((ext_vector_type(4))) int i32x4;

static constexpr int MROWS = 12608;   // 64 * 197
static constexpr int MPAD  = 12672;   // 99 * 128
static constexpr int DDIM  = 768;
static constexpr int HDIM  = 3072;

// ---- quantize: f32 -> i8 (4 elems/thread, packed store) -------------------
__device__ __forceinline__ int quant_one(float x, float K) {
    float xc = x / K;
    xc = fminf(fmaxf(xc, -1.0f), 1.0f);
    return (int)rintf(xc * 127.0f);   // v_rndne: round-half-even, matches jnp.round
}

__global__ void quant_kernel(const float* __restrict__ x, int8_t* __restrict__ q,
                             const float* __restrict__ kp, int nvalid4, int ntot4) {
    int i = blockIdx.x * 256 + threadIdx.x;
    if (i >= ntot4) return;
    int packed = 0;
    if (i < nvalid4) {
        float K = kp[0];
        float4 v = reinterpret_cast<const float4*>(x)[i];
        packed = (quant_one(v.x, K) & 255)
               | ((quant_one(v.y, K) & 255) << 8)
               | ((quant_one(v.z, K) & 255) << 16)
               | ((quant_one(v.w, K) & 255) << 24);
    }
    reinterpret_cast<int*>(q)[i] = packed;   // zero-fills padded rows
}

// ---- async global -> LDS, 16B per lane ------------------------------------
__device__ __forceinline__ void load16_to_lds(const int8_t* g, int8_t* l) {
    __builtin_amdgcn_global_load_lds(
        (const __attribute__((address_space(1))) void*)g,
        (__attribute__((address_space(3))) void*)l, 16, 0, 0);
}

// ---- i8 GEMM, 128x128 tile, BK=64, 4 waves (2x2), mfma_i32_16x16x64_i8 ----
// A: [MPAD][KD] row-major (K-major), B: [ND][KD] row-major (K-major)
// C[m,n] = sum_k A[m,k]*B[n,k]  (i32, exact)
template<int KD, int ND, bool EPI1>
__global__ __launch_bounds__(256)
void gemm_i8_kernel(const int8_t* __restrict__ A, const int8_t* __restrict__ B,
                    int8_t* __restrict__ qout, float* __restrict__ fout,
                    const float* __restrict__ bias,
                    const float* __restrict__ kA, const float* __restrict__ kW,
                    const float* __restrict__ kQ) {
    __shared__ __align__(16) int8_t Asm[128 * 64];
    __shared__ __align__(16) int8_t Bsm[128 * 64];

    const int tid  = threadIdx.x;
    const int lane = tid & 63;
    const int wave = tid >> 6;
    const int wr   = wave >> 1;      // wave row (0..1)
    const int wc   = wave & 1;       // wave col (0..1)
    const int bm   = blockIdx.y * 128;
    const int bn   = blockIdx.x * 128;

    i32x4 acc[4][4] = {};

    // staging: thread t loads row t>>2 (+64 for 2nd round), 16B chunk t&3
    const int srow = tid >> 2;
    const int scol = (tid & 3) << 4;
    const int8_t* gA = A + (size_t)(bm + srow) * KD + scol;
    const int8_t* gB = B + (size_t)(bn + srow) * KD + scol;

    // fragment addressing: lane&15 = row/col within 16x16, lane>>4 = K-chunk
    const int fr = lane & 15;
    const int kc = (lane >> 4) << 4;
    const int aoff = (wr * 64 + fr) * 64 + kc;
    const int boff = (wc * 64 + fr) * 64 + kc;

    for (int kt = 0; kt < KD; kt += 64) {
        load16_to_lds(gA + kt,                  Asm + 16 * tid);
        load16_to_lds(gA + (size_t)64 * KD + kt, Asm + 4096 + 16 * tid);
        load16_to_lds(gB + kt,                  Bsm + 16 * tid);
        load16_to_lds(gB + (size_t)64 * KD + kt, Bsm + 4096 + 16 * tid);
        __syncthreads();   // compiler drains vmcnt(0) before s_barrier

        i32x4 af[4], bf[4];
#pragma unroll
        for (int m = 0; m < 4; ++m)
            af[m] = *reinterpret_cast<const i32x4*>(Asm + aoff + m * 1024);
#pragma unroll
        for (int n = 0; n < 4; ++n)
            bf[n] = *reinterpret_cast<const i32x4*>(Bsm + boff + n * 1024);
#pragma unroll
        for (int m = 0; m < 4; ++m)
#pragma unroll
            for (int n = 0; n < 4; ++n)
                acc[m][n] = __builtin_amdgcn_mfma_i32_16x16x64_i8(af[m], bf[n], acc[m][n], 0, 0, 0);
        __syncthreads();   // protect LDS before next stage
    }

    // ---- epilogue ----
    const float sAW = kA[0] * kW[0] * (1.0f / 16129.0f);   // (kA/127)*(kW/127)
    float kq = 1.0f;
    if constexpr (EPI1) kq = kQ[0];

    const int row0 = bm + wr * 64 + ((lane >> 4) << 2);
    const int col0 = bn + wc * 64 + fr;
#pragma unroll
    for (int m = 0; m < 4; ++m) {
#pragma unroll
        for (int n = 0; n < 4; ++n) {
            const int col = col0 + n * 16;
            const float bv = bias[col];
#pragma unroll
            for (int j = 0; j < 4; ++j) {
                const int row = row0 + m * 16 + j;
                float h = (float)acc[m][n][j] * sAW + bv;
                if constexpr (EPI1) {
                    // exact-erf GELU, then re-quantize with ka2
                    float g  = 0.5f * h * (1.0f + erff(h * 0.70710678118654752f));
                    float xc = fminf(fmaxf(g / kq, -1.0f), 1.0f);
                    qout[(size_t)row * ND + col] = (int8_t)(int)rintf(xc * 127.0f);
                } else {
                    if (row < MROWS)
                        fout[(size_t)row * ND + col] = h;
                }
            }
        }
    }
}

// ---------------------------------------------------------------------------
extern "C" void kernel_launch(void* const* d_in, const int* in_sizes, int n_in,
                              void* d_out, int out_size, void* d_ws, size_t ws_size,
                              hipStream_t stream) {
    const float* hidden = (const float*)d_in[0];
    const float* W1     = (const float*)d_in[1];
    const float* b1     = (const float*)d_in[2];
    const float* W2     = (const float*)d_in[3];
    const float* b2     = (const float*)d_in[4];
    const float* ka1    = (const float*)d_in[5];
    const float* kw1    = (const float*)d_in[6];
    const float* ka2    = (const float*)d_in[7];
    const float* kw2    = (const float*)d_in[8];
    float* out = (float*)d_out;

    int8_t* a8  = (int8_t*)d_ws;                    //  [MPAD][DDIM]   9.73 MB
    int8_t* w1q = a8  + (size_t)MPAD * DDIM;        //  [HDIM][DDIM]   2.36 MB
    int8_t* w2q = w1q + (size_t)HDIM * DDIM;        //  [DDIM][HDIM]   2.36 MB
    int8_t* h8  = w2q + (size_t)DDIM * HDIM;        //  [MPAD][HDIM]  38.93 MB

    // 1) quantize activations (zero-pad rows MROWS..MPAD) and weights
    {
        int ntot4 = MPAD * DDIM / 4, nval4 = MROWS * DDIM / 4;
        quant_kernel<<<(ntot4 + 255) / 256, 256, 0, stream>>>(hidden, a8, ka1, nval4, ntot4);
    }
    {
        int n4 = HDIM * DDIM / 4;
        quant_kernel<<<(n4 + 255) / 256, 256, 0, stream>>>(W1, w1q, kw1, n4, n4);
        quant_kernel<<<(n4 + 255) / 256, 256, 0, stream>>>(W2, w2q, kw2, n4, n4);
    }

    // 2) GEMM1 + bias + gelu + quant(ka2) -> h8
    gemm_i8_kernel<DDIM, HDIM, true>
        <<<dim3(HDIM / 128, MPAD / 128), 256, 0, stream>>>
        (a8, w1q, h8, nullptr, b1, ka1, kw1, ka2);

    // 3) GEMM2 + bias -> out (f32)
    gemm_i8_kernel<HDIM, DDIM, false>
        <<<dim3(DDIM / 128, MPAD / 128), 256, 0, stream>>>
        (h8, w2q, nullptr, out, b2, ka2, kw2, nullptr);
}